// Round 12
// baseline (372.359 us; speedup 1.0000x reference)
//
#include <hip/hip_runtime.h>
#include <hip/hip_bf16.h>
#include <cstdint>
#include <cstddef>
#include <math.h>

#define NN 50000
#define NE 800000
#define INC 512
#define HIDC 256
#define NBLK ((NN + 255) / 256)

typedef __attribute__((ext_vector_type(8))) short s8v;   // 8 bf16 = 4 VGPR
typedef __attribute__((ext_vector_type(4))) float f4v;

__device__ __forceinline__ float b2f(unsigned short u) {
    return __uint_as_float(((unsigned)u) << 16);
}
__device__ __forceinline__ unsigned short f2b(float f) {
    __hip_bfloat16 h = __float2bfloat16(f);
    return *reinterpret_cast<unsigned short*>(&h);
}

// ---------------- CSR build ----------------
__global__ void k_deg_count(const int* __restrict__ dst, int* __restrict__ cnt, int e) {
    int i = blockIdx.x * 256 + threadIdx.x;
    if (i < e) atomicAdd(&cnt[dst[i]], 1);
}
__global__ void k_scan1(const int* __restrict__ cnt, int* __restrict__ excl,
                        int* __restrict__ bsum, float* __restrict__ dinv, int n) {
    __shared__ int s[256];
    int i = blockIdx.x * 256 + threadIdx.x;
    int v = (i < n) ? cnt[i] : 0;
    if (i < n) dinv[i] = rsqrtf((float)v + 1.0f);
    s[threadIdx.x] = v;
    __syncthreads();
    for (int off = 1; off < 256; off <<= 1) {
        int t = (threadIdx.x >= off) ? s[threadIdx.x - off] : 0;
        __syncthreads();
        s[threadIdx.x] += t;
        __syncthreads();
    }
    if (i < n) excl[i] = s[threadIdx.x] - v;
    if (threadIdx.x == 255) bsum[blockIdx.x] = s[255];
}
__global__ void k_scan2(int* __restrict__ bsum, int* __restrict__ bsumx, int nb) {
    __shared__ int s[256];
    int t = threadIdx.x;
    int v = (t < nb) ? bsum[t] : 0;
    s[t] = v;
    __syncthreads();
    for (int off = 1; off < 256; off <<= 1) {
        int tt = (t >= off) ? s[t - off] : 0;
        __syncthreads();
        s[t] += tt;
        __syncthreads();
    }
    if (t < nb) bsumx[t] = s[t] - v;
}
__global__ void k_scan3(int* __restrict__ rowptr, const int* __restrict__ bsumx, int n, int e) {
    int i = blockIdx.x * 256 + threadIdx.x;
    if (i < n) rowptr[i] += bsumx[blockIdx.x];
    if (i == 0) rowptr[n] = e;
}
__global__ void k_fill(const int* __restrict__ src, const int* __restrict__ dst,
                       const int* __restrict__ rowptr, int* __restrict__ cursor,
                       int* __restrict__ col, int e) {
    int i = blockIdx.x * 256 + threadIdx.x;
    if (i >= e) return;
    int d = dst[i];
    int pos = rowptr[d] + atomicAdd(&cursor[d], 1);
    col[pos] = src[i];
}

// ---------------- transposes for coalesced fold ----------------
__global__ void k_tr2(const float* __restrict__ Wg3, const float* __restrict__ Wc3,
                      float* __restrict__ Wg3t, float* __restrict__ Wc3t) {
    int t = blockIdx.x * 256 + threadIdx.x;
    if (t < 256 * 350) { int k = t / 350, i = t - k * 350; Wg3t[i * 256 + k] = Wg3[t]; }
    if (t < 350 * 350) { int i = t / 350, j = t - i * 350; Wc3t[j * 350 + i] = Wc3[t]; }
}

// ---------------- fused weight prep (plain [col][k] layouts) ----------------
// blocks 0..511: W1t[c][k] ; 512..959: Wft[j][k] (folded Wg@Wc) ; 960..961: bfv
__global__ void k_prep(const float* __restrict__ W1,
                       const float* __restrict__ Wg0, const float* __restrict__ Wc0,
                       const float* __restrict__ bg0, const float* __restrict__ bc0,
                       const float* __restrict__ Wg1, const float* __restrict__ Wc1,
                       const float* __restrict__ bg1, const float* __restrict__ bc1,
                       const float* __restrict__ Wg2, const float* __restrict__ Wc2,
                       const float* __restrict__ bg2, const float* __restrict__ bc2,
                       const float* __restrict__ Wg3, const float* __restrict__ Wc3,
                       const float* __restrict__ bg3, const float* __restrict__ bc3,
                       const float* __restrict__ Wg3t, const float* __restrict__ Wc3t,
                       unsigned short* __restrict__ W1t, unsigned short* __restrict__ Wft,
                       float* __restrict__ bfv)
{
    __shared__ float Wcj[352];
    int b = blockIdx.x, tid = threadIdx.x;
    if (b < 512) {
        int t = b * 256 + tid;            // 256*512 elems
        int c = t >> 9, k = t & 511;
        W1t[(size_t)c * 512 + k] = f2b(W1[(size_t)k * 256 + c]);
    } else if (b < 960) {
        int j = b - 512, k = tid;
        float s = 0.f;
        if (j < 350) {
            for (int i = tid; i < 350; i += 256) Wcj[i] = Wc3t[(size_t)j * 350 + i];
            __syncthreads();
            for (int i = 0; i < 350; ++i) s += Wg3t[i * 256 + k] * Wcj[i];
        } else if (j >= 352 && j < 362) {
            int jj = j - 352; for (int i = 0; i < 10; ++i) s += Wg0[k * 10 + i] * Wc0[i * 10 + jj];
        } else if (j >= 362 && j < 387) {
            int jj = j - 362; for (int i = 0; i < 25; ++i) s += Wg1[k * 25 + i] * Wc1[i * 25 + jj];
        } else if (j >= 387 && j < 403) {
            int jj = j - 387; for (int i = 0; i < 16; ++i) s += Wg2[k * 16 + i] * Wc2[i * 16 + jj];
        }
        Wft[(size_t)j * 256 + k] = f2b(s);
    } else {
        int j = (b - 960) * 256 + tid;
        if (j >= 448) return;
        float s = 0.f;
        if (j < 350)                  { s = bc3[j]; for (int i = 0; i < 350; ++i) s += bg3[i] * Wc3[(size_t)i * 350 + j]; }
        else if (j >= 352 && j < 362) { int jj = j - 352; s = bc0[jj]; for (int i = 0; i < 10; ++i) s += bg0[i] * Wc0[i * 10 + jj]; }
        else if (j >= 362 && j < 387) { int jj = j - 362; s = bc1[jj]; for (int i = 0; i < 25; ++i) s += bg1[i] * Wc1[i * 25 + jj]; }
        else if (j >= 387 && j < 403) { int jj = j - 387; s = bc2[jj]; for (int i = 0; i < 16; ++i) s += bg2[i] * Wc2[i * 16 + jj]; }
        bfv[j] = s;
    }
}

// ---------------- gemm1: xwb = bf16( fp32 X[M][512] @ W1t ), BM=128, BN=256, BK=64 ----------------
// 512 thr = 8 waves, each wave 16 rows x 256 cols. XOR(row&7) layout (proven 0-conflict).
__global__ __launch_bounds__(512) void gemm1_conv(
    const float* __restrict__ X, const unsigned short* __restrict__ Bt,
    unsigned short* __restrict__ C, int M)
{
    __shared__ s8v As[1024];   // 128 rows x 8 chunks, XOR-swizzled
    __shared__ s8v Bs[2048];   // 256 cols x 8 chunks
    const int t = threadIdx.x;
    const int lane = t & 63, wv = t >> 6;
    const int row0 = blockIdx.x * 128;
    const int l15 = lane & 15, lq = lane >> 4, l7 = lane & 7;

    f4v acc[16] = {};
    for (int k0 = 0; k0 < 512; k0 += 64) {
#pragma unroll
        for (int s = 0; s < 2; ++s) {   // A: 1024 chunks, fp32->bf16 in regs
            int c = s * 512 + t;
            int row = c >> 3, ch = c & 7;
            int chg = ch ^ (row & 7);
            int gr = row0 + row; if (gr >= M) gr = M - 1;
            const float* src = X + (size_t)gr * 512 + k0 + chg * 8;
            float4 a = *(const float4*)src;
            float4 b = *(const float4*)(src + 4);
            s8v o;
            o[0] = (short)f2b(a.x); o[1] = (short)f2b(a.y);
            o[2] = (short)f2b(a.z); o[3] = (short)f2b(a.w);
            o[4] = (short)f2b(b.x); o[5] = (short)f2b(b.y);
            o[6] = (short)f2b(b.z); o[7] = (short)f2b(b.w);
            As[c] = o;
        }
#pragma unroll
        for (int s = 0; s < 4; ++s) {   // B: 2048 chunks
            int c = s * 512 + t;
            int colr = c >> 3, ch = c & 7;
            int chg = ch ^ (colr & 7);
            Bs[c] = *(const s8v*)(Bt + (size_t)colr * 512 + k0 + chg * 8);
        }
        __syncthreads();
#pragma unroll
        for (int kk = 0; kk < 2; ++kk) {
            s8v af = As[(wv * 16 + l15) * 8 + ((kk * 4 + lq) ^ l7)];
#pragma unroll
            for (int cf = 0; cf < 16; ++cf) {
                s8v bfr = Bs[(cf * 16 + l15) * 8 + ((kk * 4 + lq) ^ l7)];
                acc[cf] = __builtin_amdgcn_mfma_f32_16x16x32_bf16(af, bfr, acc[cf], 0, 0, 0);
            }
        }
        __syncthreads();
    }
#pragma unroll
    for (int cf = 0; cf < 16; ++cf)
#pragma unroll
        for (int r = 0; r < 4; ++r) {
            int row = row0 + wv * 16 + lq * 4 + r;
            if (row < M) C[(size_t)row * 256 + cf * 16 + l15] = f2b(acc[cf][r]);
        }
}

// ---------------- gather1: 2 nodes/wave, 32 lanes x ushort8 per row ----------------
template <bool RELU, bool BIAS>
__global__ __launch_bounds__(256) void k_gather2(
    const unsigned short* __restrict__ feat, const int* __restrict__ rowptr,
    const int* __restrict__ col, const float* __restrict__ dinv,
    const float* __restrict__ bias, unsigned short* __restrict__ out, int n)
{
    int unit = (blockIdx.x * 256 + threadIdx.x) >> 5;
    int l32 = threadIdx.x & 31;
    if (unit >= n) return;
    float di = dinv[unit];
    int p0 = rowptr[unit], p1 = rowptr[unit + 1];
    int deg = p1 - p0;
    int myc = 0; float mydj = 0.f;
    if (l32 < deg) { myc = col[p0 + l32]; mydj = dinv[myc]; }
    float acc[8] = {};
    int dmin = deg < 32 ? deg : 32;
    int base = threadIdx.x & 32;
#pragma unroll 2
    for (int q = 0; q < dmin; ++q) {
        int j = __shfl(myc, base + q);
        float dj = __shfl(mydj, base + q);
        s8v v = *(const s8v*)(feat + (size_t)j * HIDC + l32 * 8);
#pragma unroll
        for (int c = 0; c < 8; ++c) acc[c] += dj * b2f((unsigned short)v[c]);
    }
    for (int p = p0 + 32; p < p1; ++p) {
        int j = col[p];
        float dj = dinv[j];
        s8v v = *(const s8v*)(feat + (size_t)j * HIDC + l32 * 8);
#pragma unroll
        for (int c = 0; c < 8; ++c) acc[c] += dj * b2f((unsigned short)v[c]);
    }
    s8v sv = *(const s8v*)(feat + (size_t)unit * HIDC + l32 * 8);
    float dd = di * di;
    s8v o;
#pragma unroll
    for (int c = 0; c < 8; ++c) {
        float r = di * acc[c] + dd * b2f((unsigned short)sv[c]);
        if (BIAS) r += bias[l32 * 8 + c];
        if (RELU) r = fmaxf(r, 0.f);
        o[c] = (short)f2b(r);
    }
    *(s8v*)(out + (size_t)unit * HIDC + l32 * 8) = o;
}

// ---------------- fused gather2 + gemm2 + 4-head softmax ----------------
// 256 thr = 4 waves, BM=64. Phase 1: gather 64 ah-rows (full K=256) into As
// (XOR(row&7) within 8-chunk groups). Phase 2: per 32-k slice stage Bs in
// plane-major-XOR layout (r8-proven 0-conflict), 28 MFMA/wave/slice, then
// r4-proven per-wave segmented-softmax epilogue. LDS 60KB -> 2 blocks/CU.
__global__ __launch_bounds__(256) void k_gg2(
    const unsigned short* __restrict__ feat, const int* __restrict__ rowptr,
    const int* __restrict__ col, const float* __restrict__ dinv,
    const unsigned short* __restrict__ Bt, const float* __restrict__ bfv,
    float* __restrict__ o0, float* __restrict__ o1,
    float* __restrict__ o2, float* __restrict__ o3, int M)
{
    __shared__ s8v As[2048];   // 64 rows x 32 chunks (full K), 32KB
    __shared__ s8v Bs[1792];   // 4 planes x 448 cols (32-k slice), 28KB
    const int t = threadIdx.x;
    const int lane = t & 63, wv = t >> 6;
    const int l32 = lane & 31, half = lane >> 5, base = lane & 32;
    const int row0 = blockIdx.x * 64;
    const int l15 = lane & 15, lq = lane >> 4, l7 = lane & 7;

    // ---- phase 1: gather ----
    for (int it = 0; it < 8; ++it) {
        int lrow = wv * 16 + it * 2 + half;
        int nd = row0 + lrow; if (nd >= M) nd = M - 1;
        float di = dinv[nd];
        int p0 = rowptr[nd], p1 = rowptr[nd + 1];
        int deg = p1 - p0;
        int myc = 0; float mydj = 0.f;
        if (l32 < deg) { myc = col[p0 + l32]; mydj = dinv[myc]; }
        float acc[8] = {};
        int dmin = deg < 32 ? deg : 32;
#pragma unroll 4
        for (int q = 0; q < dmin; ++q) {
            int j = __shfl(myc, base + q);
            float dj = __shfl(mydj, base + q);
            s8v v = *(const s8v*)(feat + (size_t)j * HIDC + l32 * 8);
#pragma unroll
            for (int c = 0; c < 8; ++c) acc[c] += dj * b2f((unsigned short)v[c]);
        }
        for (int p = p0 + 32; p < p1; ++p) {   // rare tail deg>32
            int j = col[p];
            float dj = dinv[j];
            s8v v = *(const s8v*)(feat + (size_t)j * HIDC + l32 * 8);
#pragma unroll
            for (int c = 0; c < 8; ++c) acc[c] += dj * b2f((unsigned short)v[c]);
        }
        s8v sv = *(const s8v*)(feat + (size_t)nd * HIDC + l32 * 8);
        float dd = di * di;
        s8v o;
#pragma unroll
        for (int c = 0; c < 8; ++c)
            o[c] = (short)f2b(di * acc[c] + dd * b2f((unsigned short)sv[c]));
        As[lrow * 32 + (l32 & 24) + ((l32 & 7) ^ (lrow & 7))] = o;
    }
    __syncthreads();

    // ---- phase 2: gemm ----
    f4v acc[28] = {};
    for (int kg = 0; kg < 8; ++kg) {
#pragma unroll
        for (int s = 0; s < 7; ++s) {   // stage Bs: 1792 chunks, plane-major-XOR
            int idx = s * 256 + t;
            int pl = idx & 3, cj = idx >> 2;
            Bs[pl * 448 + (cj ^ (pl * 2))] =
                *(const s8v*)(Bt + (size_t)cj * 256 + kg * 32 + pl * 8);
        }
        __syncthreads();
        s8v af = As[(wv * 16 + l15) * 32 + (kg >> 1) * 8 + (((kg & 1) * 4 + lq) ^ l7)];
#pragma unroll
        for (int cf = 0; cf < 28; ++cf) {
            s8v bfr = Bs[lq * 448 + ((cf * 16 + l15) ^ (lq * 2))];
            acc[cf] = __builtin_amdgcn_mfma_f32_16x16x32_bf16(af, bfr, acc[cf], 0, 0, 0);
        }
        __syncthreads();
    }

    // ---- epilogue: bias + 4-head segmented softmax (r4-proven) ----
#pragma unroll
    for (int cf = 0; cf < 28; ++cf) {
        float b = bfv[cf * 16 + l15];
#pragma unroll
        for (int r = 0; r < 4; ++r) acc[cf][r] += b;
    }
#pragma unroll
    for (int r = 0; r < 4; ++r) {
        int row = row0 + wv * 16 + lq * 4 + r;
        float m0 = -1e30f, m1 = -1e30f, m2 = -1e30f, m3 = -1e30f;
#pragma unroll
        for (int cf = 0; cf < 28; ++cf) {
            int colc = cf * 16 + l15;
            float xv = acc[cf][r];
            if (colc < 350) m0 = fmaxf(m0, xv);
            else if (colc >= 352 && colc < 362) m1 = fmaxf(m1, xv);
            else if (colc >= 362 && colc < 387) m2 = fmaxf(m2, xv);
            else if (colc >= 387 && colc < 403) m3 = fmaxf(m3, xv);
        }
#pragma unroll
        for (int o = 8; o; o >>= 1) {
            m0 = fmaxf(m0, __shfl_xor(m0, o));
            m1 = fmaxf(m1, __shfl_xor(m1, o));
            m2 = fmaxf(m2, __shfl_xor(m2, o));
            m3 = fmaxf(m3, __shfl_xor(m3, o));
        }
        float s0 = 0.f, s1 = 0.f, s2 = 0.f, s3 = 0.f;
#pragma unroll
        for (int cf = 0; cf < 28; ++cf) {
            int colc = cf * 16 + l15;
            float xv = acc[cf][r];
            float e = 0.f;
            if (colc < 350)                     { e = __expf(xv - m0); s0 += e; }
            else if (colc >= 352 && colc < 362) { e = __expf(xv - m1); s1 += e; }
            else if (colc >= 362 && colc < 387) { e = __expf(xv - m2); s2 += e; }
            else if (colc >= 387 && colc < 403) { e = __expf(xv - m3); s3 += e; }
            acc[cf][r] = e;
        }
#pragma unroll
        for (int o = 8; o; o >>= 1) {
            s0 += __shfl_xor(s0, o); s1 += __shfl_xor(s1, o);
            s2 += __shfl_xor(s2, o); s3 += __shfl_xor(s3, o);
        }
        float i0 = 1.f / s0, i1 = 1.f / s1, i2 = 1.f / s2, i3 = 1.f / s3;
        if (row < M) {
#pragma unroll
            for (int cf = 0; cf < 28; ++cf) {
                int colc = cf * 16 + l15;
                float e = acc[cf][r];
                if (colc < 350)                     o3[(size_t)row * 350 + colc]       = e * i0;
                else if (colc >= 352 && colc < 362) o0[(size_t)row * 10 + colc - 352]  = e * i1;
                else if (colc >= 362 && colc < 387) o1[(size_t)row * 25 + colc - 362]  = e * i2;
                else if (colc >= 387 && colc < 403) o2[(size_t)row * 16 + colc - 387]  = e * i3;
            }
        }
    }
}

// ---------------- launch ----------------
extern "C" void kernel_launch(void* const* d_in, const int* in_sizes, int n_in,
                              void* d_out, int out_size, void* d_ws, size_t ws_size,
                              hipStream_t stream)
{
    const float* x   = (const float*)d_in[0];
    const int*   ei  = (const int*)d_in[1];
    const float* W1  = (const float*)d_in[2];
    const float* b1  = (const float*)d_in[3];
    const float* Wg0 = (const float*)d_in[4];
    const float* bg0 = (const float*)d_in[5];
    const float* Wc0 = (const float*)d_in[6];
    const float* bc0 = (const float*)d_in[7];
    const float* Wg1 = (const float*)d_in[8];
    const float* bg1 = (const float*)d_in[9];
    const float* Wc1 = (const float*)d_in[10];
    const float* bc1 = (const float*)d_in[11];
    const float* Wg2 = (const float*)d_in[12];
    const float* bg2 = (const float*)d_in[13];
    const float* Wc2 = (const float*)d_in[14];
    const float* bc2 = (const float*)d_in[15];
    const float* Wg3 = (const float*)d_in[16];
    const float* bg3 = (const float*)d_in[17];
    const float* Wc3 = (const float*)d_in[18];
    const float* bc3 = (const float*)d_in[19];
    const int* srcI = ei;
    const int* dstI = ei + NE;

    char* ws = (char*)d_ws;
    size_t off = 0;
    auto alloc = [&](size_t bytes) { void* p = ws + off; off += (bytes + 255) & ~(size_t)255; return p; };
    float* dinv   = (float*)alloc(50176 * 4);
    int*   rowptr = (int*)  alloc(50432 * 4);
    int*   cnt    = (int*)  alloc(2 * 50176 * 4);
    int*   cursor = cnt + 50176;
    int*   bsum   = (int*)  alloc(1024);
    int*   bsumx  = (int*)  alloc(1024);
    int*   col    = (int*)  alloc((size_t)NE * 4);
    unsigned short* W1t = (unsigned short*)alloc(256 * 512 * 2);
    unsigned short* Wft = (unsigned short*)alloc(448 * 256 * 2);
    float* bfv   = (float*)alloc(448 * 4);
    float* Wg3t  = (float*)alloc(350 * 256 * 4);
    float* Wc3t  = (float*)alloc(350 * 350 * 4);
    unsigned short* xwb = (unsigned short*)alloc((size_t)NN * HIDC * 2);
    unsigned short* hb  = (unsigned short*)alloc((size_t)NN * HIDC * 2);

    float* out0 = (float*)d_out;
    float* out1 = out0 + (size_t)NN * 10;
    float* out2 = out1 + (size_t)NN * 25;
    float* out3 = out2 + (size_t)NN * 16;

    // ---- CSR build ----
    hipMemsetAsync(cnt, 0, 2 * 50176 * 4, stream);
    k_deg_count<<<(NE + 255) / 256, 256, 0, stream>>>(dstI, cnt, NE);
    k_scan1<<<NBLK, 256, 0, stream>>>(cnt, rowptr, bsum, dinv, NN);
    k_scan2<<<1, 256, 0, stream>>>(bsum, bsumx, NBLK);
    k_scan3<<<NBLK, 256, 0, stream>>>(rowptr, bsumx, NN, NE);
    k_fill<<<(NE + 255) / 256, 256, 0, stream>>>(srcI, dstI, rowptr, cursor, col, NE);

    // ---- weight prep ----
    k_tr2<<<(350 * 350 + 255) / 256, 256, 0, stream>>>(Wg3, Wc3, Wg3t, Wc3t);
    k_prep<<<962, 256, 0, stream>>>(W1,
                                    Wg0, Wc0, bg0, bc0, Wg1, Wc1, bg1, bc1,
                                    Wg2, Wc2, bg2, bc2, Wg3, Wc3, bg3, bc3,
                                    Wg3t, Wc3t, W1t, Wft, bfv);

    // ---- pipeline ----
    gemm1_conv<<<(NN + 127) / 128, 512, 0, stream>>>(x, W1t, xwb, NN);
    k_gather2<true, true><<<(NN + 7) / 8, 256, 0, stream>>>(xwb, rowptr, col, dinv, b1, hb, NN);
    k_gg2<<<(NN + 63) / 64, 256, 0, stream>>>(hb, rowptr, col, dinv, Wft, bfv,
                                              out0, out1, out2, out3, NN);
}

// Round 13
// 325.462 us; speedup vs baseline: 1.1441x; 1.1441x over previous
//
#include <hip/hip_runtime.h>
#include <hip/hip_bf16.h>
#include <cstdint>
#include <cstddef>
#include <math.h>

#define NN 50000
#define NE 800000
#define INC 512
#define HIDC 256
#define NBLK ((NN + 255) / 256)

typedef __attribute__((ext_vector_type(8))) short s8v;   // 8 bf16 = 4 VGPR
typedef __attribute__((ext_vector_type(4))) float f4v;

__device__ __forceinline__ float b2f(unsigned short u) {
    return __uint_as_float(((unsigned)u) << 16);
}
__device__ __forceinline__ unsigned short f2b(float f) {
    __hip_bfloat16 h = __float2bfloat16(f);
    return *reinterpret_cast<unsigned short*>(&h);
}

// ---------------- CSR build ----------------
__global__ void k_deg_count(const int* __restrict__ dst, int* __restrict__ cnt, int e) {
    int i = blockIdx.x * 256 + threadIdx.x;
    if (i < e) atomicAdd(&cnt[dst[i]], 1);
}
__global__ void k_scan1(const int* __restrict__ cnt, int* __restrict__ excl,
                        int* __restrict__ bsum, float* __restrict__ dinv, int n) {
    __shared__ int s[256];
    int i = blockIdx.x * 256 + threadIdx.x;
    int v = (i < n) ? cnt[i] : 0;
    if (i < n) dinv[i] = rsqrtf((float)v + 1.0f);
    s[threadIdx.x] = v;
    __syncthreads();
    for (int off = 1; off < 256; off <<= 1) {
        int t = (threadIdx.x >= off) ? s[threadIdx.x - off] : 0;
        __syncthreads();
        s[threadIdx.x] += t;
        __syncthreads();
    }
    if (i < n) excl[i] = s[threadIdx.x] - v;
    if (threadIdx.x == 255) bsum[blockIdx.x] = s[255];
}
// scan3 with fused block-offset reduction (replaces old scan2+scan3)
__global__ void k_scan3(int* __restrict__ rowptr, const int* __restrict__ bsum, int n, int e) {
    __shared__ int sred[4];
    int b = blockIdx.x, t = threadIdx.x;
    int v = (t < b) ? bsum[t] : 0;     // b <= 195 < 256
    for (int o = 32; o; o >>= 1) v += __shfl_xor(v, o);
    if ((t & 63) == 0) sred[t >> 6] = v;
    __syncthreads();
    int off = sred[0] + sred[1] + sred[2] + sred[3];
    int i = b * 256 + t;
    if (i < n) rowptr[i] += off;
    if (i == 0) rowptr[n] = e;
}
__global__ void k_fill(const int* __restrict__ src, const int* __restrict__ dst,
                       const int* __restrict__ rowptr, int* __restrict__ cursor,
                       int* __restrict__ col, int e) {
    int i = blockIdx.x * 256 + threadIdx.x;
    if (i >= e) return;
    int d = dst[i];
    int pos = rowptr[d] + atomicAdd(&cursor[d], 1);
    col[pos] = src[i];
}

// ---------------- transposes for coalesced fold ----------------
__global__ void k_tr2(const float* __restrict__ Wg3, const float* __restrict__ Wc3,
                      float* __restrict__ Wg3t, float* __restrict__ Wc3t) {
    int t = blockIdx.x * 256 + threadIdx.x;
    if (t < 256 * 350) { int k = t / 350, i = t - k * 350; Wg3t[i * 256 + k] = Wg3[t]; }
    if (t < 350 * 350) { int i = t / 350, j = t - i * 350; Wc3t[j * 350 + i] = Wc3[t]; }
}

// ---------------- fused weight prep (plain [col][k] layouts) ----------------
// blocks 0..511: W1t[c][k] ; 512..959: Wft[j][k] (folded Wg@Wc) ; 960..961: bfv
__global__ void k_prep(const float* __restrict__ W1,
                       const float* __restrict__ Wg0, const float* __restrict__ Wc0,
                       const float* __restrict__ bg0, const float* __restrict__ bc0,
                       const float* __restrict__ Wg1, const float* __restrict__ Wc1,
                       const float* __restrict__ bg1, const float* __restrict__ bc1,
                       const float* __restrict__ Wg2, const float* __restrict__ Wc2,
                       const float* __restrict__ bg2, const float* __restrict__ bc2,
                       const float* __restrict__ Wg3, const float* __restrict__ Wc3,
                       const float* __restrict__ bg3, const float* __restrict__ bc3,
                       const float* __restrict__ Wg3t, const float* __restrict__ Wc3t,
                       unsigned short* __restrict__ W1t, unsigned short* __restrict__ Wft,
                       float* __restrict__ bfv)
{
    __shared__ float Wcj[352];
    int b = blockIdx.x, tid = threadIdx.x;
    if (b < 512) {
        int t = b * 256 + tid;            // 256*512 elems
        int c = t >> 9, k = t & 511;
        W1t[(size_t)c * 512 + k] = f2b(W1[(size_t)k * 256 + c]);
    } else if (b < 960) {
        int j = b - 512, k = tid;
        float s = 0.f;
        if (j < 350) {
            for (int i = tid; i < 350; i += 256) Wcj[i] = Wc3t[(size_t)j * 350 + i];
            __syncthreads();
            for (int i = 0; i < 350; ++i) s += Wg3t[i * 256 + k] * Wcj[i];
        } else if (j >= 352 && j < 362) {
            int jj = j - 352; for (int i = 0; i < 10; ++i) s += Wg0[k * 10 + i] * Wc0[i * 10 + jj];
        } else if (j >= 362 && j < 387) {
            int jj = j - 362; for (int i = 0; i < 25; ++i) s += Wg1[k * 25 + i] * Wc1[i * 25 + jj];
        } else if (j >= 387 && j < 403) {
            int jj = j - 387; for (int i = 0; i < 16; ++i) s += Wg2[k * 16 + i] * Wc2[i * 16 + jj];
        }
        Wft[(size_t)j * 256 + k] = f2b(s);
    } else {
        int j = (b - 960) * 256 + tid;
        if (j >= 448) return;
        float s = 0.f;
        if (j < 350)                  { s = bc3[j]; for (int i = 0; i < 350; ++i) s += bg3[i] * Wc3[(size_t)i * 350 + j]; }
        else if (j >= 352 && j < 362) { int jj = j - 352; s = bc0[jj]; for (int i = 0; i < 10; ++i) s += bg0[i] * Wc0[i * 10 + jj]; }
        else if (j >= 362 && j < 387) { int jj = j - 362; s = bc1[jj]; for (int i = 0; i < 25; ++i) s += bg1[i] * Wc1[i * 25 + jj]; }
        else if (j >= 387 && j < 403) { int jj = j - 387; s = bc2[jj]; for (int i = 0; i < 16; ++i) s += bg2[i] * Wc2[i * 16 + jj]; }
        bfv[j] = s;
    }
}

// ---------------- gemm1: xwb = bf16( fp32 X[M][512] @ W1t ), BM=128, BN=256, BK=64 ----------------
// 512 thr = 8 waves, each wave 16 rows x 256 cols. XOR(row&7) layout (proven 0-conflict).
__global__ __launch_bounds__(512) void gemm1_conv(
    const float* __restrict__ X, const unsigned short* __restrict__ Bt,
    unsigned short* __restrict__ C, int M)
{
    __shared__ s8v As[1024];   // 128 rows x 8 chunks, XOR-swizzled
    __shared__ s8v Bs[2048];   // 256 cols x 8 chunks
    const int t = threadIdx.x;
    const int lane = t & 63, wv = t >> 6;
    const int row0 = blockIdx.x * 128;
    const int l15 = lane & 15, lq = lane >> 4, l7 = lane & 7;

    f4v acc[16] = {};
    for (int k0 = 0; k0 < 512; k0 += 64) {
#pragma unroll
        for (int s = 0; s < 2; ++s) {   // A: 1024 chunks, fp32->bf16 in regs
            int c = s * 512 + t;
            int row = c >> 3, ch = c & 7;
            int chg = ch ^ (row & 7);
            int gr = row0 + row; if (gr >= M) gr = M - 1;
            const float* src = X + (size_t)gr * 512 + k0 + chg * 8;
            float4 a = *(const float4*)src;
            float4 b = *(const float4*)(src + 4);
            s8v o;
            o[0] = (short)f2b(a.x); o[1] = (short)f2b(a.y);
            o[2] = (short)f2b(a.z); o[3] = (short)f2b(a.w);
            o[4] = (short)f2b(b.x); o[5] = (short)f2b(b.y);
            o[6] = (short)f2b(b.z); o[7] = (short)f2b(b.w);
            As[c] = o;
        }
#pragma unroll
        for (int s = 0; s < 4; ++s) {   // B: 2048 chunks
            int c = s * 512 + t;
            int colr = c >> 3, ch = c & 7;
            int chg = ch ^ (colr & 7);
            Bs[c] = *(const s8v*)(Bt + (size_t)colr * 512 + k0 + chg * 8);
        }
        __syncthreads();
#pragma unroll
        for (int kk = 0; kk < 2; ++kk) {
            s8v af = As[(wv * 16 + l15) * 8 + ((kk * 4 + lq) ^ l7)];
#pragma unroll
            for (int cf = 0; cf < 16; ++cf) {
                s8v bfr = Bs[(cf * 16 + l15) * 8 + ((kk * 4 + lq) ^ l7)];
                acc[cf] = __builtin_amdgcn_mfma_f32_16x16x32_bf16(af, bfr, acc[cf], 0, 0, 0);
            }
        }
        __syncthreads();
    }
#pragma unroll
    for (int cf = 0; cf < 16; ++cf)
#pragma unroll
        for (int r = 0; r < 4; ++r) {
            int row = row0 + wv * 16 + lq * 4 + r;
            if (row < M) C[(size_t)row * 256 + cf * 16 + l15] = f2b(acc[cf][r]);
        }
}

// ---------------- gather: 2 nodes/wave, 32 lanes x ushort8 per row, 8 rows in flight ----------------
template <bool RELU, bool BIAS>
__global__ __launch_bounds__(256) void k_gather2(
    const unsigned short* __restrict__ feat, const int* __restrict__ rowptr,
    const int* __restrict__ col, const float* __restrict__ dinv,
    const float* __restrict__ bias, unsigned short* __restrict__ out, int n)
{
    int unit = (blockIdx.x * 256 + threadIdx.x) >> 5;
    int l32 = threadIdx.x & 31;
    if (unit >= n) return;
    float di = dinv[unit];
    int p0 = rowptr[unit], p1 = rowptr[unit + 1];
    int deg = p1 - p0;
    int myc = 0; float mydj = 0.f;
    if (l32 < deg) { myc = col[p0 + l32]; mydj = dinv[myc]; }
    float acc[8] = {};
    int dmin = deg < 32 ? deg : 32;
    int base = threadIdx.x & 32;
#pragma unroll 8
    for (int q = 0; q < dmin; ++q) {
        int j = __shfl(myc, base + q);
        float dj = __shfl(mydj, base + q);
        s8v v = *(const s8v*)(feat + (size_t)j * HIDC + l32 * 8);
#pragma unroll
        for (int c = 0; c < 8; ++c) acc[c] += dj * b2f((unsigned short)v[c]);
    }
    for (int p = p0 + 32; p < p1; ++p) {
        int j = col[p];
        float dj = dinv[j];
        s8v v = *(const s8v*)(feat + (size_t)j * HIDC + l32 * 8);
#pragma unroll
        for (int c = 0; c < 8; ++c) acc[c] += dj * b2f((unsigned short)v[c]);
    }
    s8v sv = *(const s8v*)(feat + (size_t)unit * HIDC + l32 * 8);
    float dd = di * di;
    s8v o;
#pragma unroll
    for (int c = 0; c < 8; ++c) {
        float r = di * acc[c] + dd * b2f((unsigned short)sv[c]);
        if (BIAS) r += bias[l32 * 8 + c];
        if (RELU) r = fmaxf(r, 0.f);
        o[c] = (short)f2b(r);
    }
    *(s8v*)(out + (size_t)unit * HIDC + l32 * 8) = o;
}

// ---------------- gemm2 + 4-head softmax: BM=128, BN=448, BK=64, 512 thr ----------------
// 8 waves, each wave 16 rows x 448 cols (acc[28]); per-wave softmax epilogue (r4-proven).
__global__ __launch_bounds__(512) void gemm2_heads(
    const unsigned short* __restrict__ A, const unsigned short* __restrict__ Bt,
    const float* __restrict__ bfv,
    float* __restrict__ o0, float* __restrict__ o1,
    float* __restrict__ o2, float* __restrict__ o3, int M)
{
    __shared__ s8v As[1024];   // 128 x 8
    __shared__ s8v Bs[3584];   // 448 x 8
    const int t = threadIdx.x;
    const int lane = t & 63, wv = t >> 6;
    const int row0 = blockIdx.x * 128;
    const int l15 = lane & 15, lq = lane >> 4, l7 = lane & 7;

    f4v acc[28] = {};
    for (int k0 = 0; k0 < 256; k0 += 64) {
#pragma unroll
        for (int s = 0; s < 2; ++s) {   // A: 1024 chunks
            int c = s * 512 + t;
            int row = c >> 3, ch = c & 7;
            int chg = ch ^ (row & 7);
            int gr = row0 + row; if (gr >= M) gr = M - 1;
            As[c] = *(const s8v*)(A + (size_t)gr * 256 + k0 + chg * 8);
        }
#pragma unroll
        for (int s = 0; s < 7; ++s) {   // B: 3584 chunks
            int c = s * 512 + t;
            int colr = c >> 3, ch = c & 7;
            int chg = ch ^ (colr & 7);
            Bs[c] = *(const s8v*)(Bt + (size_t)colr * 256 + k0 + chg * 8);
        }
        __syncthreads();
#pragma unroll
        for (int kk = 0; kk < 2; ++kk) {
            s8v af = As[(wv * 16 + l15) * 8 + ((kk * 4 + lq) ^ l7)];
#pragma unroll
            for (int cf = 0; cf < 28; ++cf) {
                s8v bfr = Bs[(cf * 16 + l15) * 8 + ((kk * 4 + lq) ^ l7)];
                acc[cf] = __builtin_amdgcn_mfma_f32_16x16x32_bf16(af, bfr, acc[cf], 0, 0, 0);
            }
        }
        __syncthreads();
    }
    // fold bias in
#pragma unroll
    for (int cf = 0; cf < 28; ++cf) {
        float b = bfv[cf * 16 + l15];
#pragma unroll
        for (int r = 0; r < 4; ++r) acc[cf][r] += b;
    }
    // per-row 4-head segmented softmax; row r of frag held by 16 lanes (lq group)
#pragma unroll
    for (int r = 0; r < 4; ++r) {
        int row = row0 + wv * 16 + lq * 4 + r;
        float m0 = -1e30f, m1 = -1e30f, m2 = -1e30f, m3 = -1e30f;
#pragma unroll
        for (int cf = 0; cf < 28; ++cf) {
            int colc = cf * 16 + l15;
            float xv = acc[cf][r];
            if (colc < 350) m0 = fmaxf(m0, xv);
            else if (colc >= 352 && colc < 362) m1 = fmaxf(m1, xv);
            else if (colc >= 362 && colc < 387) m2 = fmaxf(m2, xv);
            else if (colc >= 387 && colc < 403) m3 = fmaxf(m3, xv);
        }
#pragma unroll
        for (int o = 8; o; o >>= 1) {
            m0 = fmaxf(m0, __shfl_xor(m0, o));
            m1 = fmaxf(m1, __shfl_xor(m1, o));
            m2 = fmaxf(m2, __shfl_xor(m2, o));
            m3 = fmaxf(m3, __shfl_xor(m3, o));
        }
        float s0 = 0.f, s1 = 0.f, s2 = 0.f, s3 = 0.f;
#pragma unroll
        for (int cf = 0; cf < 28; ++cf) {
            int colc = cf * 16 + l15;
            float xv = acc[cf][r];
            float e = 0.f;
            if (colc < 350)                     { e = __expf(xv - m0); s0 += e; }
            else if (colc >= 352 && colc < 362) { e = __expf(xv - m1); s1 += e; }
            else if (colc >= 362 && colc < 387) { e = __expf(xv - m2); s2 += e; }
            else if (colc >= 387 && colc < 403) { e = __expf(xv - m3); s3 += e; }
            acc[cf][r] = e;
        }
#pragma unroll
        for (int o = 8; o; o >>= 1) {
            s0 += __shfl_xor(s0, o); s1 += __shfl_xor(s1, o);
            s2 += __shfl_xor(s2, o); s3 += __shfl_xor(s3, o);
        }
        float i0 = 1.f / s0, i1 = 1.f / s1, i2 = 1.f / s2, i3 = 1.f / s3;
        if (row < M) {
#pragma unroll
            for (int cf = 0; cf < 28; ++cf) {
                int colc = cf * 16 + l15;
                float e = acc[cf][r];
                if (colc < 350)                     o3[(size_t)row * 350 + colc]       = e * i0;
                else if (colc >= 352 && colc < 362) o0[(size_t)row * 10 + colc - 352]  = e * i1;
                else if (colc >= 362 && colc < 387) o1[(size_t)row * 25 + colc - 362]  = e * i2;
                else if (colc >= 387 && colc < 403) o2[(size_t)row * 16 + colc - 387]  = e * i3;
            }
        }
    }
}

// ---------------- launch ----------------
extern "C" void kernel_launch(void* const* d_in, const int* in_sizes, int n_in,
                              void* d_out, int out_size, void* d_ws, size_t ws_size,
                              hipStream_t stream)
{
    const float* x   = (const float*)d_in[0];
    const int*   ei  = (const int*)d_in[1];
    const float* W1  = (const float*)d_in[2];
    const float* b1  = (const float*)d_in[3];
    const float* Wg0 = (const float*)d_in[4];
    const float* bg0 = (const float*)d_in[5];
    const float* Wc0 = (const float*)d_in[6];
    const float* bc0 = (const float*)d_in[7];
    const float* Wg1 = (const float*)d_in[8];
    const float* bg1 = (const float*)d_in[9];
    const float* Wc1 = (const float*)d_in[10];
    const float* bc1 = (const float*)d_in[11];
    const float* Wg2 = (const float*)d_in[12];
    const float* bg2 = (const float*)d_in[13];
    const float* Wc2 = (const float*)d_in[14];
    const float* bc2 = (const float*)d_in[15];
    const float* Wg3 = (const float*)d_in[16];
    const float* bg3 = (const float*)d_in[17];
    const float* Wc3 = (const float*)d_in[18];
    const float* bc3 = (const float*)d_in[19];
    const int* srcI = ei;
    const int* dstI = ei + NE;

    char* ws = (char*)d_ws;
    size_t off = 0;
    auto alloc = [&](size_t bytes) { void* p = ws + off; off += (bytes + 255) & ~(size_t)255; return p; };
    float* dinv   = (float*)alloc(50176 * 4);
    int*   rowptr = (int*)  alloc(50432 * 4);
    int*   cnt    = (int*)  alloc(2 * 50176 * 4);
    int*   cursor = cnt + 50176;
    int*   bsum   = (int*)  alloc(1024);
    int*   col    = (int*)  alloc((size_t)NE * 4);
    unsigned short* W1t = (unsigned short*)alloc(256 * 512 * 2);
    unsigned short* Wft = (unsigned short*)alloc(448 * 256 * 2);
    float* bfv   = (float*)alloc(448 * 4);
    float* Wg3t  = (float*)alloc(350 * 256 * 4);
    float* Wc3t  = (float*)alloc(350 * 350 * 4);
    unsigned short* xwb = (unsigned short*)alloc((size_t)NN * HIDC * 2);
    unsigned short* hb  = (unsigned short*)alloc((size_t)NN * HIDC * 2);
    unsigned short* ahb = xwb;   // alias: xwb dead after gather1

    float* out0 = (float*)d_out;
    float* out1 = out0 + (size_t)NN * 10;
    float* out2 = out1 + (size_t)NN * 25;
    float* out3 = out2 + (size_t)NN * 16;

    // ---- CSR build ----
    hipMemsetAsync(cnt, 0, 2 * 50176 * 4, stream);
    k_deg_count<<<(NE + 255) / 256, 256, 0, stream>>>(dstI, cnt, NE);
    k_scan1<<<NBLK, 256, 0, stream>>>(cnt, rowptr, bsum, dinv, NN);
    k_scan3<<<NBLK, 256, 0, stream>>>(rowptr, bsum, NN, NE);
    k_fill<<<(NE + 255) / 256, 256, 0, stream>>>(srcI, dstI, rowptr, cursor, col, NE);

    // ---- weight prep ----
    k_tr2<<<(350 * 350 + 255) / 256, 256, 0, stream>>>(Wg3, Wc3, Wg3t, Wc3t);
    k_prep<<<962, 256, 0, stream>>>(W1,
                                    Wg0, Wc0, bg0, bc0, Wg1, Wc1, bg1, bc1,
                                    Wg2, Wc2, bg2, bc2, Wg3, Wc3, bg3, bc3,
                                    Wg3t, Wc3t, W1t, Wft, bfv);

    // ---- pipeline ----
    gemm1_conv<<<(NN + 127) / 128, 512, 0, stream>>>(x, W1t, xwb, NN);
    k_gather2<true, true><<<(NN + 7) / 8, 256, 0, stream>>>(xwb, rowptr, col, dinv, b1, hb, NN);
    k_gather2<false, false><<<(NN + 7) / 8, 256, 0, stream>>>(hb, rowptr, col, dinv, nullptr, ahb, NN);
    gemm2_heads<<<(NN + 127) / 128, 512, 0, stream>>>(ahb, Wft, bfv, out0, out1, out2, out3, NN);
}

// Round 14
// 311.190 us; speedup vs baseline: 1.1966x; 1.0459x over previous
//
#include <hip/hip_runtime.h>
#include <hip/hip_bf16.h>
#include <cstdint>
#include <cstddef>
#include <math.h>

#define NN 50000
#define NE 800000
#define INC 512
#define HIDC 256
#define NBLK ((NN + 255) / 256)      // 196
#define NB_DEG ((NE + 255) / 256)    // 3125
#define NB_TR2 ((350 * 350 + 255) / 256)  // 479

typedef __attribute__((ext_vector_type(8))) short s8v;   // 8 bf16 = 4 VGPR
typedef __attribute__((ext_vector_type(4))) float f4v;

__device__ __forceinline__ float b2f(unsigned short u) {
    return __uint_as_float(((unsigned)u) << 16);
}
__device__ __forceinline__ unsigned short f2b(float f) {
    __hip_bfloat16 h = __float2bfloat16(f);
    return *reinterpret_cast<unsigned short*>(&h);
}

// ================= M1: deg_count (blocks 0..3124) || tr2 (blocks 3125..3603) =================
__global__ void k_front1(const int* __restrict__ dst, int* __restrict__ cnt,
                         const float* __restrict__ Wg3, const float* __restrict__ Wc3,
                         float* __restrict__ Wg3t, float* __restrict__ Wc3t)
{
    if (blockIdx.x < NB_DEG) {
        int i = blockIdx.x * 256 + threadIdx.x;
        if (i < NE) atomicAdd(&cnt[dst[i]], 1);
    } else {
        int t = (blockIdx.x - NB_DEG) * 256 + threadIdx.x;
        if (t < 256 * 350) { int k = t / 350, i = t - k * 350; Wg3t[i * 256 + k] = Wg3[t]; }
        if (t < 350 * 350) { int i = t / 350, j = t - i * 350; Wc3t[j * 350 + i] = Wc3[t]; }
    }
}

// ================= M2: scan1+dinv (blocks 0..195) || prep (blocks 196..1157) =================
__global__ void k_front2(const int* __restrict__ cnt, int* __restrict__ excl,
                         int* __restrict__ bsum, float* __restrict__ dinv,
                         const float* __restrict__ W1,
                         const float* __restrict__ Wg0, const float* __restrict__ Wc0,
                         const float* __restrict__ bg0, const float* __restrict__ bc0,
                         const float* __restrict__ Wg1, const float* __restrict__ Wc1,
                         const float* __restrict__ bg1, const float* __restrict__ bc1,
                         const float* __restrict__ Wg2, const float* __restrict__ Wc2,
                         const float* __restrict__ bg2, const float* __restrict__ bc2,
                         const float* __restrict__ Wg3, const float* __restrict__ Wc3,
                         const float* __restrict__ bg3, const float* __restrict__ bc3,
                         const float* __restrict__ Wg3t, const float* __restrict__ Wc3t,
                         unsigned short* __restrict__ W1t, unsigned short* __restrict__ Wft,
                         float* __restrict__ bfv)
{
    __shared__ float shm[352];
    int tid = threadIdx.x;
    if (blockIdx.x < NBLK) {
        // ---- scan1 + dinv ----
        int* s = (int*)shm;
        int i = blockIdx.x * 256 + tid;
        int v = (i < NN) ? cnt[i] : 0;
        if (i < NN) dinv[i] = rsqrtf((float)v + 1.0f);
        s[tid] = v;
        __syncthreads();
        for (int off = 1; off < 256; off <<= 1) {
            int t = (tid >= off) ? s[tid - off] : 0;
            __syncthreads();
            s[tid] += t;
            __syncthreads();
        }
        if (i < NN) excl[i] = s[tid] - v;
        if (tid == 255) bsum[blockIdx.x] = s[255];
        return;
    }
    int b = blockIdx.x - NBLK;   // 0..961 (prep)
    if (b < 512) {
        int t = b * 256 + tid;
        int c = t >> 9, k = t & 511;
        W1t[(size_t)c * 512 + k] = f2b(W1[(size_t)k * 256 + c]);
    } else if (b < 960) {
        int j = b - 512, k = tid;
        float s = 0.f;
        if (j < 350) {
            for (int i = tid; i < 350; i += 256) shm[i] = Wc3t[(size_t)j * 350 + i];
            __syncthreads();
            for (int i = 0; i < 350; ++i) s += Wg3t[i * 256 + k] * shm[i];
        } else if (j >= 352 && j < 362) {
            int jj = j - 352; for (int i = 0; i < 10; ++i) s += Wg0[k * 10 + i] * Wc0[i * 10 + jj];
        } else if (j >= 362 && j < 387) {
            int jj = j - 362; for (int i = 0; i < 25; ++i) s += Wg1[k * 25 + i] * Wc1[i * 25 + jj];
        } else if (j >= 387 && j < 403) {
            int jj = j - 387; for (int i = 0; i < 16; ++i) s += Wg2[k * 16 + i] * Wc2[i * 16 + jj];
        }
        Wft[(size_t)j * 256 + k] = f2b(s);
    } else {
        int j = (b - 960) * 256 + tid;
        if (j >= 448) return;
        float s = 0.f;
        if (j < 350)                  { s = bc3[j]; for (int i = 0; i < 350; ++i) s += bg3[i] * Wc3[(size_t)i * 350 + j]; }
        else if (j >= 352 && j < 362) { int jj = j - 352; s = bc0[jj]; for (int i = 0; i < 10; ++i) s += bg0[i] * Wc0[i * 10 + jj]; }
        else if (j >= 362 && j < 387) { int jj = j - 362; s = bc1[jj]; for (int i = 0; i < 25; ++i) s += bg1[i] * Wc1[i * 25 + jj]; }
        else if (j >= 387 && j < 403) { int jj = j - 387; s = bc2[jj]; for (int i = 0; i < 16; ++i) s += bg2[i] * Wc2[i * 16 + jj]; }
        bfv[j] = s;
    }
}

// ================= M3: gemm1 (blocks 0..390) || scan3 (blocks 391..586), 512 thr =================
// gemm1: xwb = bf16( fp32 X[M][512] @ W1t ), BM=128, BN=256, BK=64 — r11-proven.
#define GEMM1_NB ((NN + 127) / 128)   // 391
__global__ __launch_bounds__(512) void k_front3(
    const float* __restrict__ X, const unsigned short* __restrict__ Bt,
    unsigned short* __restrict__ C,
    int* __restrict__ rowptr, const int* __restrict__ bsum, int M)
{
    __shared__ s8v As[1024];   // 128 rows x 8 chunks, XOR-swizzled (16KB)
    __shared__ s8v Bs[2048];   // 256 cols x 8 chunks (32KB)
    const int t = threadIdx.x;

    if (blockIdx.x >= GEMM1_NB) {
        // ---- scan3: fused block-offset reduction (512-thread variant) ----
        int* sred = (int*)As;
        int b = blockIdx.x - GEMM1_NB;     // 0..195
        int v = (t < b) ? bsum[t] : 0;     // b <= 195 < 512
        for (int o = 32; o; o >>= 1) v += __shfl_xor(v, o);
        if ((t & 63) == 0) sred[t >> 6] = v;
        __syncthreads();
        int off = 0;
#pragma unroll
        for (int w = 0; w < 8; ++w) off += sred[w];
        if (t < 256) {
            int i = b * 256 + t;
            if (i < NN) rowptr[i] += off;
            if (i == 0) rowptr[NN] = NE;
        }
        return;
    }

    const int lane = t & 63, wv = t >> 6;
    const int row0 = blockIdx.x * 128;
    const int l15 = lane & 15, lq = lane >> 4, l7 = lane & 7;

    f4v acc[16] = {};
    for (int k0 = 0; k0 < 512; k0 += 64) {
#pragma unroll
        for (int s = 0; s < 2; ++s) {   // A: 1024 chunks, fp32->bf16 in regs
            int c = s * 512 + t;
            int row = c >> 3, ch = c & 7;
            int chg = ch ^ (row & 7);
            int gr = row0 + row; if (gr >= M) gr = M - 1;
            const float* src = X + (size_t)gr * 512 + k0 + chg * 8;
            float4 a = *(const float4*)src;
            float4 b = *(const float4*)(src + 4);
            s8v o;
            o[0] = (short)f2b(a.x); o[1] = (short)f2b(a.y);
            o[2] = (short)f2b(a.z); o[3] = (short)f2b(a.w);
            o[4] = (short)f2b(b.x); o[5] = (short)f2b(b.y);
            o[6] = (short)f2b(b.z); o[7] = (short)f2b(b.w);
            As[c] = o;
        }
#pragma unroll
        for (int s = 0; s < 4; ++s) {   // B: 2048 chunks
            int c = s * 512 + t;
            int colr = c >> 3, ch = c & 7;
            int chg = ch ^ (colr & 7);
            Bs[c] = *(const s8v*)(Bt + (size_t)colr * 512 + k0 + chg * 8);
        }
        __syncthreads();
#pragma unroll
        for (int kk = 0; kk < 2; ++kk) {
            s8v af = As[(wv * 16 + l15) * 8 + ((kk * 4 + lq) ^ l7)];
#pragma unroll
            for (int cf = 0; cf < 16; ++cf) {
                s8v bfr = Bs[(cf * 16 + l15) * 8 + ((kk * 4 + lq) ^ l7)];
                acc[cf] = __builtin_amdgcn_mfma_f32_16x16x32_bf16(af, bfr, acc[cf], 0, 0, 0);
            }
        }
        __syncthreads();
    }
#pragma unroll
    for (int cf = 0; cf < 16; ++cf)
#pragma unroll
        for (int r = 0; r < 4; ++r) {
            int row = row0 + wv * 16 + lq * 4 + r;
            if (row < M) C[(size_t)row * 256 + cf * 16 + l15] = f2b(acc[cf][r]);
        }
}

// ================= M4: CSR fill =================
__global__ void k_fill(const int* __restrict__ src, const int* __restrict__ dst,
                       const int* __restrict__ rowptr, int* __restrict__ cursor,
                       int* __restrict__ col, int e) {
    int i = blockIdx.x * 256 + threadIdx.x;
    if (i >= e) return;
    int d = dst[i];
    int pos = rowptr[d] + atomicAdd(&cursor[d], 1);
    col[pos] = src[i];
}

// ---------------- gather: 2 nodes/wave, 32 lanes x ushort8 per row ----------------
template <bool RELU, bool BIAS>
__global__ __launch_bounds__(256) void k_gather2(
    const unsigned short* __restrict__ feat, const int* __restrict__ rowptr,
    const int* __restrict__ col, const float* __restrict__ dinv,
    const float* __restrict__ bias, unsigned short* __restrict__ out, int n)
{
    int unit = (blockIdx.x * 256 + threadIdx.x) >> 5;
    int l32 = threadIdx.x & 31;
    if (unit >= n) return;
    float di = dinv[unit];
    int p0 = rowptr[unit], p1 = rowptr[unit + 1];
    int deg = p1 - p0;
    int myc = 0; float mydj = 0.f;
    if (l32 < deg) { myc = col[p0 + l32]; mydj = dinv[myc]; }
    float acc[8] = {};
    int dmin = deg < 32 ? deg : 32;
    int base = threadIdx.x & 32;
#pragma unroll 8
    for (int q = 0; q < dmin; ++q) {
        int j = __shfl(myc, base + q);
        float dj = __shfl(mydj, base + q);
        s8v v = *(const s8v*)(feat + (size_t)j * HIDC + l32 * 8);
#pragma unroll
        for (int c = 0; c < 8; ++c) acc[c] += dj * b2f((unsigned short)v[c]);
    }
    for (int p = p0 + 32; p < p1; ++p) {
        int j = col[p];
        float dj = dinv[j];
        s8v v = *(const s8v*)(feat + (size_t)j * HIDC + l32 * 8);
#pragma unroll
        for (int c = 0; c < 8; ++c) acc[c] += dj * b2f((unsigned short)v[c]);
    }
    s8v sv = *(const s8v*)(feat + (size_t)unit * HIDC + l32 * 8);
    float dd = di * di;
    s8v o;
#pragma unroll
    for (int c = 0; c < 8; ++c) {
        float r = di * acc[c] + dd * b2f((unsigned short)sv[c]);
        if (BIAS) r += bias[l32 * 8 + c];
        if (RELU) r = fmaxf(r, 0.f);
        o[c] = (short)f2b(r);
    }
    *(s8v*)(out + (size_t)unit * HIDC + l32 * 8) = o;
}

// ---------------- gemm2 + 4-head softmax: BM=128, BN=448, BK=64, 512 thr (r11-proven) ----------------
__global__ __launch_bounds__(512) void gemm2_heads(
    const unsigned short* __restrict__ A, const unsigned short* __restrict__ Bt,
    const float* __restrict__ bfv,
    float* __restrict__ o0, float* __restrict__ o1,
    float* __restrict__ o2, float* __restrict__ o3, int M)
{
    __shared__ s8v As[1024];   // 128 x 8
    __shared__ s8v Bs[3584];   // 448 x 8
    const int t = threadIdx.x;
    const int lane = t & 63, wv = t >> 6;
    const int row0 = blockIdx.x * 128;
    const int l15 = lane & 15, lq = lane >> 4, l7 = lane & 7;

    f4v acc[28] = {};
    for (int k0 = 0; k0 < 256; k0 += 64) {
#pragma unroll
        for (int s = 0; s < 2; ++s) {   // A: 1024 chunks
            int c = s * 512 + t;
            int row = c >> 3, ch = c & 7;
            int chg = ch ^ (row & 7);
            int gr = row0 + row; if (gr >= M) gr = M - 1;
            As[c] = *(const s8v*)(A + (size_t)gr * 256 + k0 + chg * 8);
        }
#pragma unroll
        for (int s = 0; s < 7; ++s) {   // B: 3584 chunks
            int c = s * 512 + t;
            int colr = c >> 3, ch = c & 7;
            int chg = ch ^ (colr & 7);
            Bs[c] = *(const s8v*)(Bt + (size_t)colr * 256 + k0 + chg * 8);
        }
        __syncthreads();
#pragma unroll
        for (int kk = 0; kk < 2; ++kk) {
            s8v af = As[(wv * 16 + l15) * 8 + ((kk * 4 + lq) ^ l7)];
#pragma unroll
            for (int cf = 0; cf < 28; ++cf) {
                s8v bfr = Bs[(cf * 16 + l15) * 8 + ((kk * 4 + lq) ^ l7)];
                acc[cf] = __builtin_amdgcn_mfma_f32_16x16x32_bf16(af, bfr, acc[cf], 0, 0, 0);
            }
        }
        __syncthreads();
    }
    // fold bias in
#pragma unroll
    for (int cf = 0; cf < 28; ++cf) {
        float b = bfv[cf * 16 + l15];
#pragma unroll
        for (int r = 0; r < 4; ++r) acc[cf][r] += b;
    }
    // per-row 4-head segmented softmax; row r of frag held by 16 lanes (lq group)
#pragma unroll
    for (int r = 0; r < 4; ++r) {
        int row = row0 + wv * 16 + lq * 4 + r;
        float m0 = -1e30f, m1 = -1e30f, m2 = -1e30f, m3 = -1e30f;
#pragma unroll
        for (int cf = 0; cf < 28; ++cf) {
            int colc = cf * 16 + l15;
            float xv = acc[cf][r];
            if (colc < 350) m0 = fmaxf(m0, xv);
            else if (colc >= 352 && colc < 362) m1 = fmaxf(m1, xv);
            else if (colc >= 362 && colc < 387) m2 = fmaxf(m2, xv);
            else if (colc >= 387 && colc < 403) m3 = fmaxf(m3, xv);
        }
#pragma unroll
        for (int o = 8; o; o >>= 1) {
            m0 = fmaxf(m0, __shfl_xor(m0, o));
            m1 = fmaxf(m1, __shfl_xor(m1, o));
            m2 = fmaxf(m2, __shfl_xor(m2, o));
            m3 = fmaxf(m3, __shfl_xor(m3, o));
        }
        float s0 = 0.f, s1 = 0.f, s2 = 0.f, s3 = 0.f;
#pragma unroll
        for (int cf = 0; cf < 28; ++cf) {
            int colc = cf * 16 + l15;
            float xv = acc[cf][r];
            float e = 0.f;
            if (colc < 350)                     { e = __expf(xv - m0); s0 += e; }
            else if (colc >= 352 && colc < 362) { e = __expf(xv - m1); s1 += e; }
            else if (colc >= 362 && colc < 387) { e = __expf(xv - m2); s2 += e; }
            else if (colc >= 387 && colc < 403) { e = __expf(xv - m3); s3 += e; }
            acc[cf][r] = e;
        }
#pragma unroll
        for (int o = 8; o; o >>= 1) {
            s0 += __shfl_xor(s0, o); s1 += __shfl_xor(s1, o);
            s2 += __shfl_xor(s2, o); s3 += __shfl_xor(s3, o);
        }
        float i0 = 1.f / s0, i1 = 1.f / s1, i2 = 1.f / s2, i3 = 1.f / s3;
        if (row < M) {
#pragma unroll
            for (int cf = 0; cf < 28; ++cf) {
                int colc = cf * 16 + l15;
                float e = acc[cf][r];
                if (colc < 350)                     o3[(size_t)row * 350 + colc]       = e * i0;
                else if (colc >= 352 && colc < 362) o0[(size_t)row * 10 + colc - 352]  = e * i1;
                else if (colc >= 362 && colc < 387) o1[(size_t)row * 25 + colc - 362]  = e * i2;
                else if (colc >= 387 && colc < 403) o2[(size_t)row * 16 + colc - 387]  = e * i3;
            }
        }
    }
}

// ---------------- launch ----------------
extern "C" void kernel_launch(void* const* d_in, const int* in_sizes, int n_in,
                              void* d_out, int out_size, void* d_ws, size_t ws_size,
                              hipStream_t stream)
{
    const float* x   = (const float*)d_in[0];
    const int*   ei  = (const int*)d_in[1];
    const float* W1  = (const float*)d_in[2];
    const float* b1  = (const float*)d_in[3];
    const float* Wg0 = (const float*)d_in[4];
    const float* bg0 = (const float*)d_in[5];
    const float* Wc0 = (const float*)d_in[6];
    const float* bc0 = (const float*)d_in[7];
    const float* Wg1 = (const float*)d_in[8];
    const float* bg1 = (const float*)d_in[9];
    const float* Wc1 = (const float*)d_in[10];
    const float* bc1 = (const float*)d_in[11];
    const float* Wg2 = (const float*)d_in[12];
    const float* bg2 = (const float*)d_in[13];
    const float* Wc2 = (const float*)d_in[14];
    const float* bc2 = (const float*)d_in[15];
    const float* Wg3 = (const float*)d_in[16];
    const float* bg3 = (const float*)d_in[17];
    const float* Wc3 = (const float*)d_in[18];
    const float* bc3 = (const float*)d_in[19];
    const int* srcI = ei;
    const int* dstI = ei + NE;

    char* ws = (char*)d_ws;
    size_t off = 0;
    auto alloc = [&](size_t bytes) { void* p = ws + off; off += (bytes + 255) & ~(size_t)255; return p; };
    float* dinv   = (float*)alloc(50176 * 4);
    int*   rowptr = (int*)  alloc(50432 * 4);
    int*   cnt    = (int*)  alloc(2 * 50176 * 4);
    int*   cursor = cnt + 50176;
    int*   bsum   = (int*)  alloc(1024);
    int*   col    = (int*)  alloc((size_t)NE * 4);
    unsigned short* W1t = (unsigned short*)alloc(256 * 512 * 2);
    unsigned short* Wft = (unsigned short*)alloc(448 * 256 * 2);
    float* bfv   = (float*)alloc(448 * 4);
    float* Wg3t  = (float*)alloc(350 * 256 * 4);
    float* Wc3t  = (float*)alloc(350 * 350 * 4);
    unsigned short* xwb = (unsigned short*)alloc((size_t)NN * HIDC * 2);
    unsigned short* hb  = (unsigned short*)alloc((size_t)NN * HIDC * 2);
    unsigned short* ahb = xwb;   // alias: xwb dead after gather1

    float* out0 = (float*)d_out;
    float* out1 = out0 + (size_t)NN * 10;
    float* out2 = out1 + (size_t)NN * 25;
    float* out3 = out2 + (size_t)NN * 16;

    hipMemsetAsync(cnt, 0, 2 * 50176 * 4, stream);

    // M1: deg_count || tr2
    k_front1<<<NB_DEG + NB_TR2, 256, 0, stream>>>(dstI, cnt, Wg3, Wc3, Wg3t, Wc3t);
    // M2: scan1+dinv || prep
    k_front2<<<NBLK + 962, 256, 0, stream>>>(cnt, rowptr, bsum, dinv, W1,
                                             Wg0, Wc0, bg0, bc0, Wg1, Wc1, bg1, bc1,
                                             Wg2, Wc2, bg2, bc2, Wg3, Wc3, bg3, bc3,
                                             Wg3t, Wc3t, W1t, Wft, bfv);
    // M3: gemm1 || scan3
    k_front3<<<GEMM1_NB + NBLK, 512, 0, stream>>>(x, W1t, xwb, rowptr, bsum, NN);
    // M4: fill
    k_fill<<<NB_DEG, 256, 0, stream>>>(srcI, dstI, rowptr, cursor, col, NE);

    // gathers + gemm2
    k_gather2<true, true><<<(NN + 7) / 8, 256, 0, stream>>>(xwb, rowptr, col, dinv, b1, hb, NN);
    k_gather2<false, false><<<(NN + 7) / 8, 256, 0, stream>>>(hb, rowptr, col, dinv, nullptr, ahb, NN);
    gemm2_heads<<<(NN + 127) / 128, 512, 0, stream>>>(ahb, Wft, bfv, out0, out1, out2, out3, NN);
}

// Round 15
// 302.624 us; speedup vs baseline: 1.2304x; 1.0283x over previous
//
#include <hip/hip_runtime.h>
#include <hip/hip_bf16.h>
#include <cstdint>
#include <cstddef>
#include <math.h>

#define NN 50000
#define NE 800000
#define INC 512
#define HIDC 256
#define NBLK ((NN + 255) / 256)      // 196
#define NB_DEG ((NE + 255) / 256)    // 3125
#define NB_TR2 ((350 * 350 + 255) / 256)  // 479

typedef __attribute__((ext_vector_type(8))) short s8v;   // 8 bf16 = 4 VGPR
typedef __attribute__((ext_vector_type(4))) float f4v;

__device__ __forceinline__ float b2f(unsigned short u) {
    return __uint_as_float(((unsigned)u) << 16);
}
__device__ __forceinline__ unsigned short f2b(float f) {
    __hip_bfloat16 h = __float2bfloat16(f);
    return *reinterpret_cast<unsigned short*>(&h);
}

// ================= M1: deg_count (blocks 0..3124) || tr2 (blocks 3125..3603) =================
__global__ void k_front1(const int* __restrict__ dst, int* __restrict__ cnt,
                         const float* __restrict__ Wg3, const float* __restrict__ Wc3,
                         float* __restrict__ Wg3t, float* __restrict__ Wc3t)
{
    if (blockIdx.x < NB_DEG) {
        int i = blockIdx.x * 256 + threadIdx.x;
        if (i < NE) atomicAdd(&cnt[dst[i]], 1);
    } else {
        int t = (blockIdx.x - NB_DEG) * 256 + threadIdx.x;
        if (t < 256 * 350) { int k = t / 350, i = t - k * 350; Wg3t[i * 256 + k] = Wg3[t]; }
        if (t < 350 * 350) { int i = t / 350, j = t - i * 350; Wc3t[j * 350 + i] = Wc3[t]; }
    }
}

// ================= M2: scan1+dinv (blocks 0..195) || prep (blocks 196..1157) =================
__global__ void k_front2(const int* __restrict__ cnt, int* __restrict__ excl,
                         int* __restrict__ bsum, float* __restrict__ dinv,
                         const float* __restrict__ W1,
                         const float* __restrict__ Wg0, const float* __restrict__ Wc0,
                         const float* __restrict__ bg0, const float* __restrict__ bc0,
                         const float* __restrict__ Wg1, const float* __restrict__ Wc1,
                         const float* __restrict__ bg1, const float* __restrict__ bc1,
                         const float* __restrict__ Wg2, const float* __restrict__ Wc2,
                         const float* __restrict__ bg2, const float* __restrict__ bc2,
                         const float* __restrict__ Wg3, const float* __restrict__ Wc3,
                         const float* __restrict__ bg3, const float* __restrict__ bc3,
                         const float* __restrict__ Wg3t, const float* __restrict__ Wc3t,
                         unsigned short* __restrict__ W1t, unsigned short* __restrict__ Wft,
                         float* __restrict__ bfv)
{
    __shared__ float shm[352];
    int tid = threadIdx.x;
    if (blockIdx.x < NBLK) {
        int* s = (int*)shm;
        int i = blockIdx.x * 256 + tid;
        int v = (i < NN) ? cnt[i] : 0;
        if (i < NN) dinv[i] = rsqrtf((float)v + 1.0f);
        s[tid] = v;
        __syncthreads();
        for (int off = 1; off < 256; off <<= 1) {
            int t = (tid >= off) ? s[tid - off] : 0;
            __syncthreads();
            s[tid] += t;
            __syncthreads();
        }
        if (i < NN) excl[i] = s[tid] - v;
        if (tid == 255) bsum[blockIdx.x] = s[255];
        return;
    }
    int b = blockIdx.x - NBLK;   // 0..961 (prep)
    if (b < 512) {
        int t = b * 256 + tid;
        int c = t >> 9, k = t & 511;
        W1t[(size_t)c * 512 + k] = f2b(W1[(size_t)k * 256 + c]);
    } else if (b < 960) {
        int j = b - 512, k = tid;
        float s = 0.f;
        if (j < 350) {
            for (int i = tid; i < 350; i += 256) shm[i] = Wc3t[(size_t)j * 350 + i];
            __syncthreads();
            for (int i = 0; i < 350; ++i) s += Wg3t[i * 256 + k] * shm[i];
        } else if (j >= 352 && j < 362) {
            int jj = j - 352; for (int i = 0; i < 10; ++i) s += Wg0[k * 10 + i] * Wc0[i * 10 + jj];
        } else if (j >= 362 && j < 387) {
            int jj = j - 362; for (int i = 0; i < 25; ++i) s += Wg1[k * 25 + i] * Wc1[i * 25 + jj];
        } else if (j >= 387 && j < 403) {
            int jj = j - 387; for (int i = 0; i < 16; ++i) s += Wg2[k * 16 + i] * Wc2[i * 16 + jj];
        }
        Wft[(size_t)j * 256 + k] = f2b(s);
    } else {
        int j = (b - 960) * 256 + tid;
        if (j >= 448) return;
        float s = 0.f;
        if (j < 350)                  { s = bc3[j]; for (int i = 0; i < 350; ++i) s += bg3[i] * Wc3[(size_t)i * 350 + j]; }
        else if (j >= 352 && j < 362) { int jj = j - 352; s = bc0[jj]; for (int i = 0; i < 10; ++i) s += bg0[i] * Wc0[i * 10 + jj]; }
        else if (j >= 362 && j < 387) { int jj = j - 362; s = bc1[jj]; for (int i = 0; i < 25; ++i) s += bg1[i] * Wc1[i * 25 + jj]; }
        else if (j >= 387 && j < 403) { int jj = j - 387; s = bc2[jj]; for (int i = 0; i < 16; ++i) s += bg2[i] * Wc2[i * 16 + jj]; }
        bfv[j] = s;
    }
}

// ================= M3: scan3 (block-offset reduction), standalone tiny =================
__global__ void k_scan3(int* __restrict__ rowptr, const int* __restrict__ bsum, int n, int e) {
    __shared__ int sred[4];
    int b = blockIdx.x, t = threadIdx.x;
    int v = (t < b) ? bsum[t] : 0;     // b <= 195 < 256
    for (int o = 32; o; o >>= 1) v += __shfl_xor(v, o);
    if ((t & 63) == 0) sred[t >> 6] = v;
    __syncthreads();
    int off = sred[0] + sred[1] + sred[2] + sred[3];
    int i = b * 256 + t;
    if (i < n) rowptr[i] += off;
    if (i == 0) rowptr[n] = e;
}

// ================= M4: gemm1 (blocks 0..390) || fill (blocks 391..1953), 512 thr =================
// gemm1: xwb = bf16( fp32 X[M][512] @ W1t ), BM=128, BN=256, BK=64 — r11-proven.
#define GEMM1_NB ((NN + 127) / 128)   // 391
#define FILL_NB ((NE + 511) / 512)    // 1563
__global__ __launch_bounds__(512) void k_front4(
    const float* __restrict__ X, const unsigned short* __restrict__ Bt,
    unsigned short* __restrict__ C,
    const int* __restrict__ src, const int* __restrict__ dst,
    const int* __restrict__ rowptr, int* __restrict__ cursor,
    int* __restrict__ col, int M)
{
    __shared__ s8v As[1024];   // 128 rows x 8 chunks, XOR-swizzled (16KB)
    __shared__ s8v Bs[2048];   // 256 cols x 8 chunks (32KB)
    const int t = threadIdx.x;

    if (blockIdx.x >= GEMM1_NB) {
        // ---- CSR fill ----
        int i = (blockIdx.x - GEMM1_NB) * 512 + t;
        if (i < NE) {
            int d = dst[i];
            int pos = rowptr[d] + atomicAdd(&cursor[d], 1);
            col[pos] = src[i];
        }
        return;
    }

    const int lane = t & 63, wv = t >> 6;
    const int row0 = blockIdx.x * 128;
    const int l15 = lane & 15, lq = lane >> 4, l7 = lane & 7;

    f4v acc[16] = {};
    for (int k0 = 0; k0 < 512; k0 += 64) {
#pragma unroll
        for (int s = 0; s < 2; ++s) {   // A: 1024 chunks, fp32->bf16 in regs
            int c = s * 512 + t;
            int row = c >> 3, ch = c & 7;
            int chg = ch ^ (row & 7);
            int gr = row0 + row; if (gr >= M) gr = M - 1;
            const float* srcp = X + (size_t)gr * 512 + k0 + chg * 8;
            float4 a = *(const float4*)srcp;
            float4 b = *(const float4*)(srcp + 4);
            s8v o;
            o[0] = (short)f2b(a.x); o[1] = (short)f2b(a.y);
            o[2] = (short)f2b(a.z); o[3] = (short)f2b(a.w);
            o[4] = (short)f2b(b.x); o[5] = (short)f2b(b.y);
            o[6] = (short)f2b(b.z); o[7] = (short)f2b(b.w);
            As[c] = o;
        }
#pragma unroll
        for (int s = 0; s < 4; ++s) {   // B: 2048 chunks
            int c = s * 512 + t;
            int colr = c >> 3, ch = c & 7;
            int chg = ch ^ (colr & 7);
            Bs[c] = *(const s8v*)(Bt + (size_t)colr * 512 + k0 + chg * 8);
        }
        __syncthreads();
#pragma unroll
        for (int kk = 0; kk < 2; ++kk) {
            s8v af = As[(wv * 16 + l15) * 8 + ((kk * 4 + lq) ^ l7)];
#pragma unroll
            for (int cf = 0; cf < 16; ++cf) {
                s8v bfr = Bs[(cf * 16 + l15) * 8 + ((kk * 4 + lq) ^ l7)];
                acc[cf] = __builtin_amdgcn_mfma_f32_16x16x32_bf16(af, bfr, acc[cf], 0, 0, 0);
            }
        }
        __syncthreads();
    }
#pragma unroll
    for (int cf = 0; cf < 16; ++cf)
#pragma unroll
        for (int r = 0; r < 4; ++r) {
            int row = row0 + wv * 16 + lq * 4 + r;
            if (row < M) C[(size_t)row * 256 + cf * 16 + l15] = f2b(acc[cf][r]);
        }
}

// ---------------- gather: 2 nodes/wave, 32 lanes x ushort8 per row ----------------
template <bool RELU, bool BIAS>
__global__ __launch_bounds__(256) void k_gather2(
    const unsigned short* __restrict__ feat, const int* __restrict__ rowptr,
    const int* __restrict__ col, const float* __restrict__ dinv,
    const float* __restrict__ bias, unsigned short* __restrict__ out, int n)
{
    int unit = (blockIdx.x * 256 + threadIdx.x) >> 5;
    int l32 = threadIdx.x & 31;
    if (unit >= n) return;
    float di = dinv[unit];
    int p0 = rowptr[unit], p1 = rowptr[unit + 1];
    int deg = p1 - p0;
    int myc = 0; float mydj = 0.f;
    if (l32 < deg) { myc = col[p0 + l32]; mydj = dinv[myc]; }
    float acc[8] = {};
    int dmin = deg < 32 ? deg : 32;
    int base = threadIdx.x & 32;
#pragma unroll 8
    for (int q = 0; q < dmin; ++q) {
        int j = __shfl(myc, base + q);
        float dj = __shfl(mydj, base + q);
        s8v v = *(const s8v*)(feat + (size_t)j * HIDC + l32 * 8);
#pragma unroll
        for (int c = 0; c < 8; ++c) acc[c] += dj * b2f((unsigned short)v[c]);
    }
    for (int p = p0 + 32; p < p1; ++p) {
        int j = col[p];
        float dj = dinv[j];
        s8v v = *(const s8v*)(feat + (size_t)j * HIDC + l32 * 8);
#pragma unroll
        for (int c = 0; c < 8; ++c) acc[c] += dj * b2f((unsigned short)v[c]);
    }
    s8v sv = *(const s8v*)(feat + (size_t)unit * HIDC + l32 * 8);
    float dd = di * di;
    s8v o;
#pragma unroll
    for (int c = 0; c < 8; ++c) {
        float r = di * acc[c] + dd * b2f((unsigned short)sv[c]);
        if (BIAS) r += bias[l32 * 8 + c];
        if (RELU) r = fmaxf(r, 0.f);
        o[c] = (short)f2b(r);
    }
    *(s8v*)(out + (size_t)unit * HIDC + l32 * 8) = o;
}

// ---------------- gemm2 + 4-head softmax: BM=128, BN=448, BK=64, 512 thr (r11-proven) ----------------
__global__ __launch_bounds__(512) void gemm2_heads(
    const unsigned short* __restrict__ A, const unsigned short* __restrict__ Bt,
    const float* __restrict__ bfv,
    float* __restrict__ o0, float* __restrict__ o1,
    float* __restrict__ o2, float* __restrict__ o3, int M)
{
    __shared__ s8v As[1024];   // 128 x 8
    __shared__ s8v Bs[3584];   // 448 x 8
    const int t = threadIdx.x;
    const int lane = t & 63, wv = t >> 6;
    const int row0 = blockIdx.x * 128;
    const int l15 = lane & 15, lq = lane >> 4, l7 = lane & 7;

    f4v acc[28] = {};
    for (int k0 = 0; k0 < 256; k0 += 64) {
#pragma unroll
        for (int s = 0; s < 2; ++s) {   // A: 1024 chunks
            int c = s * 512 + t;
            int row = c >> 3, ch = c & 7;
            int chg = ch ^ (row & 7);
            int gr = row0 + row; if (gr >= M) gr = M - 1;
            As[c] = *(const s8v*)(A + (size_t)gr * 256 + k0 + chg * 8);
        }
#pragma unroll
        for (int s = 0; s < 7; ++s) {   // B: 3584 chunks
            int c = s * 512 + t;
            int colr = c >> 3, ch = c & 7;
            int chg = ch ^ (colr & 7);
            Bs[c] = *(const s8v*)(Bt + (size_t)colr * 256 + k0 + chg * 8);
        }
        __syncthreads();
#pragma unroll
        for (int kk = 0; kk < 2; ++kk) {
            s8v af = As[(wv * 16 + l15) * 8 + ((kk * 4 + lq) ^ l7)];
#pragma unroll
            for (int cf = 0; cf < 28; ++cf) {
                s8v bfr = Bs[(cf * 16 + l15) * 8 + ((kk * 4 + lq) ^ l7)];
                acc[cf] = __builtin_amdgcn_mfma_f32_16x16x32_bf16(af, bfr, acc[cf], 0, 0, 0);
            }
        }
        __syncthreads();
    }
    // fold bias in
#pragma unroll
    for (int cf = 0; cf < 28; ++cf) {
        float b = bfv[cf * 16 + l15];
#pragma unroll
        for (int r = 0; r < 4; ++r) acc[cf][r] += b;
    }
    // per-row 4-head segmented softmax; row r of frag held by 16 lanes (lq group)
#pragma unroll
    for (int r = 0; r < 4; ++r) {
        int row = row0 + wv * 16 + lq * 4 + r;
        float m0 = -1e30f, m1 = -1e30f, m2 = -1e30f, m3 = -1e30f;
#pragma unroll
        for (int cf = 0; cf < 28; ++cf) {
            int colc = cf * 16 + l15;
            float xv = acc[cf][r];
            if (colc < 350) m0 = fmaxf(m0, xv);
            else if (colc >= 352 && colc < 362) m1 = fmaxf(m1, xv);
            else if (colc >= 362 && colc < 387) m2 = fmaxf(m2, xv);
            else if (colc >= 387 && colc < 403) m3 = fmaxf(m3, xv);
        }
#pragma unroll
        for (int o = 8; o; o >>= 1) {
            m0 = fmaxf(m0, __shfl_xor(m0, o));
            m1 = fmaxf(m1, __shfl_xor(m1, o));
            m2 = fmaxf(m2, __shfl_xor(m2, o));
            m3 = fmaxf(m3, __shfl_xor(m3, o));
        }
        float s0 = 0.f, s1 = 0.f, s2 = 0.f, s3 = 0.f;
#pragma unroll
        for (int cf = 0; cf < 28; ++cf) {
            int colc = cf * 16 + l15;
            float xv = acc[cf][r];
            float e = 0.f;
            if (colc < 350)                     { e = __expf(xv - m0); s0 += e; }
            else if (colc >= 352 && colc < 362) { e = __expf(xv - m1); s1 += e; }
            else if (colc >= 362 && colc < 387) { e = __expf(xv - m2); s2 += e; }
            else if (colc >= 387 && colc < 403) { e = __expf(xv - m3); s3 += e; }
            acc[cf][r] = e;
        }
#pragma unroll
        for (int o = 8; o; o >>= 1) {
            s0 += __shfl_xor(s0, o); s1 += __shfl_xor(s1, o);
            s2 += __shfl_xor(s2, o); s3 += __shfl_xor(s3, o);
        }
        float i0 = 1.f / s0, i1 = 1.f / s1, i2 = 1.f / s2, i3 = 1.f / s3;
        if (row < M) {
#pragma unroll
            for (int cf = 0; cf < 28; ++cf) {
                int colc = cf * 16 + l15;
                float e = acc[cf][r];
                if (colc < 350)                     o3[(size_t)row * 350 + colc]       = e * i0;
                else if (colc >= 352 && colc < 362) o0[(size_t)row * 10 + colc - 352]  = e * i1;
                else if (colc >= 362 && colc < 387) o1[(size_t)row * 25 + colc - 362]  = e * i2;
                else if (colc >= 387 && colc < 403) o2[(size_t)row * 16 + colc - 387]  = e * i3;
            }
        }
    }
}

// ---------------- launch ----------------
extern "C" void kernel_launch(void* const* d_in, const int* in_sizes, int n_in,
                              void* d_out, int out_size, void* d_ws, size_t ws_size,
                              hipStream_t stream)
{
    const float* x   = (const float*)d_in[0];
    const int*   ei  = (const int*)d_in[1];
    const float* W1  = (const float*)d_in[2];
    const float* b1  = (const float*)d_in[3];
    const float* Wg0 = (const float*)d_in[4];
    const float* bg0 = (const float*)d_in[5];
    const float* Wc0 = (const float*)d_in[6];
    const float* bc0 = (const float*)d_in[7];
    const float* Wg1 = (const float*)d_in[8];
    const float* bg1 = (const float*)d_in[9];
    const float* Wc1 = (const float*)d_in[10];
    const float* bc1 = (const float*)d_in[11];
    const float* Wg2 = (const float*)d_in[12];
    const float* bg2 = (const float*)d_in[13];
    const float* Wc2 = (const float*)d_in[14];
    const float* bc2 = (const float*)d_in[15];
    const float* Wg3 = (const float*)d_in[16];
    const float* bg3 = (const float*)d_in[17];
    const float* Wc3 = (const float*)d_in[18];
    const float* bc3 = (const float*)d_in[19];
    const int* srcI = ei;
    const int* dstI = ei + NE;

    char* ws = (char*)d_ws;
    size_t off = 0;
    auto alloc = [&](size_t bytes) { void* p = ws + off; off += (bytes + 255) & ~(size_t)255; return p; };
    float* dinv   = (float*)alloc(50176 * 4);
    int*   rowptr = (int*)  alloc(50432 * 4);
    int*   cnt    = (int*)  alloc(2 * 50176 * 4);
    int*   cursor = cnt + 50176;
    int*   bsum   = (int*)  alloc(1024);
    int*   col    = (int*)  alloc((size_t)NE * 4);
    unsigned short* W1t = (unsigned short*)alloc(256 * 512 * 2);
    unsigned short* Wft = (unsigned short*)alloc(448 * 256 * 2);
    float* bfv   = (float*)alloc(448 * 4);
    float* Wg3t  = (float*)alloc(350 * 256 * 4);
    float* Wc3t  = (float*)alloc(350 * 350 * 4);
    unsigned short* xwb = (unsigned short*)alloc((size_t)NN * HIDC * 2);
    unsigned short* hb  = (unsigned short*)alloc((size_t)NN * HIDC * 2);
    unsigned short* ahb = xwb;   // alias: xwb dead after gather1

    float* out0 = (float*)d_out;
    float* out1 = out0 + (size_t)NN * 10;
    float* out2 = out1 + (size_t)NN * 25;
    float* out3 = out2 + (size_t)NN * 16;

    hipMemsetAsync(cnt, 0, 2 * 50176 * 4, stream);

    // M1: deg_count || tr2
    k_front1<<<NB_DEG + NB_TR2, 256, 0, stream>>>(dstI, cnt, Wg3, Wc3, Wg3t, Wc3t);
    // M2: scan1+dinv || prep
    k_front2<<<NBLK + 962, 256, 0, stream>>>(cnt, rowptr, bsum, dinv, W1,
                                             Wg0, Wc0, bg0, bc0, Wg1, Wc1, bg1, bc1,
                                             Wg2, Wc2, bg2, bc2, Wg3, Wc3, bg3, bc3,
                                             Wg3t, Wc3t, W1t, Wft, bfv);
    // M3: scan3 (tiny)
    k_scan3<<<NBLK, 256, 0, stream>>>(rowptr, bsum, NN, NE);
    // M4: gemm1 || fill
    k_front4<<<GEMM1_NB + FILL_NB, 512, 0, stream>>>(x, W1t, xwb, srcI, dstI,
                                                     rowptr, cursor, col, NN);

    // gathers + gemm2
    k_gather2<true, true><<<(NN + 7) / 8, 256, 0, stream>>>(xwb, rowptr, col, dinv, b1, hb, NN);
    k_gather2<false, false><<<(NN + 7) / 8, 256, 0, stream>>>(hb, rowptr, col, dinv, nullptr, ahb, NN);
    gemm2_heads<<<(NN + 127) / 128, 512, 0, stream>>>(ahb, Wft, bfv, out0, out1, out2, out3, NN);
}